// Round 1
// baseline (151.664 us; speedup 1.0000x reference)
//
#include <hip/hip_runtime.h>
#include <hip/hip_bf16.h>

// CausalSelfAttention quirk kernel: softmax over QUERY axis, scale sqrt(D_OUT)=32.
// Factorization: w[q,k] = exp(S/32)/Z[k], Z[k] = sum_{q>=k} exp(S/32)  (per-COLUMN).
// Pass A computes Zinv[k]; pass B recomputes S tiles and does PV.

typedef __attribute__((ext_vector_type(8))) short short8;
typedef __attribute__((ext_vector_type(4))) float floatx4;

#define NB 2
#define SS 2048
#define DIN 1024
#define DOUT 1024
#define NH 16
#define HD 64
#define SCALE 0.03125f   // 1/sqrt(D_OUT) = 1/32

#define MFMA16(a,b,c) __builtin_amdgcn_mfma_f32_16x16x32_bf16((a),(b),(c),0,0,0)

__device__ __forceinline__ void gl_lds16(const void* g, void* l) {
  __builtin_amdgcn_global_load_lds((const __attribute__((address_space(1))) void*)g,
                                   (__attribute__((address_space(3))) void*)l, 16, 0, 0);
}

// ---- convert x fp32 -> bf16 ----
__global__ __launch_bounds__(256) void k_cvt_x(const float* __restrict__ x,
                                               __hip_bfloat16* __restrict__ xb) {
  size_t i = ((size_t)blockIdx.x * 256 + threadIdx.x) * 4;
  float4 v = *(const float4*)(x + i);
  union { __hip_bfloat16 h[4]; short4 s; } u;
  u.h[0] = __float2bfloat16(v.x); u.h[1] = __float2bfloat16(v.y);
  u.h[2] = __float2bfloat16(v.z); u.h[3] = __float2bfloat16(v.w);
  *(short4*)(xb + i) = u.s;
}

// ---- transpose + convert W [k][c] fp32 -> Wt [c][k] bf16 ----
__global__ void k_twb(const float* __restrict__ W, __hip_bfloat16* __restrict__ Wt) {
  __shared__ float t[32][33];
  int tx = threadIdx.x, ty = threadIdx.y;
  int k0 = blockIdx.y * 32, c0 = blockIdx.x * 32;
#pragma unroll
  for (int i = 0; i < 4; ++i)
    t[ty + 8*i][tx] = W[(size_t)(k0 + ty + 8*i) * DOUT + c0 + tx];
  __syncthreads();
#pragma unroll
  for (int i = 0; i < 4; ++i)
    Wt[(size_t)(c0 + ty + 8*i) * DIN + k0 + tx] = __float2bfloat16(t[tx][ty + 8*i]);
}

// ---- QKV GEMM: xb[4096x1024] @ W -> heads layout.
// q,k: [b][h][s][d] ; v: [b][h][d][s] (transposed for PV B-operand) ----
__global__ __launch_bounds__(256) void k_qkv(
    const __hip_bfloat16* __restrict__ xb,
    const __hip_bfloat16* __restrict__ wq, const __hip_bfloat16* __restrict__ wk,
    const __hip_bfloat16* __restrict__ wv,
    __hip_bfloat16* __restrict__ qb, __hip_bfloat16* __restrict__ kb,
    __hip_bfloat16* __restrict__ vb) {
  __shared__ __hip_bfloat16 At[128 * 32];
  __shared__ __hip_bfloat16 Bt[128 * 32];
  const __hip_bfloat16* wt; __hip_bfloat16* out; int vmode = 0;
  if (blockIdx.z == 0)      { wt = wq; out = qb; }
  else if (blockIdx.z == 1) { wt = wk; out = kb; }
  else                      { wt = wv; out = vb; vmode = 1; }

  const int tid = threadIdx.x, w = tid >> 6, l = tid & 63;
  const int row0 = blockIdx.y * 128, col0 = blockIdx.x * 128;
  const int mw = (w >> 1) * 64, nw = (w & 1) * 64;

  const floatx4 fz = {0.f, 0.f, 0.f, 0.f};
  floatx4 acc[4][4];
#pragma unroll
  for (int m = 0; m < 4; ++m)
#pragma unroll
    for (int n = 0; n < 4; ++n) acc[m][n] = fz;

  for (int kk = 0; kk < DIN; kk += 32) {
#pragma unroll
    for (int i = 0; i < 2; ++i) {
      int c = w * 2 + i;
      int r = c * 16 + (l >> 2), cc = (l & 3) * 8;
      gl_lds16(xb + (size_t)(row0 + r) * DIN + kk + cc, &At[c * 512]);
      gl_lds16(wt + (size_t)(col0 + r) * DIN + kk + cc, &Bt[c * 512]);
    }
    __syncthreads();
    short8 a[4], bfr[4];
#pragma unroll
    for (int m = 0; m < 4; ++m)
      a[m] = *(const short8*)&At[(mw + m * 16 + (l & 15)) * 32 + (l >> 4) * 8];
#pragma unroll
    for (int n = 0; n < 4; ++n)
      bfr[n] = *(const short8*)&Bt[(nw + n * 16 + (l & 15)) * 32 + (l >> 4) * 8];
#pragma unroll
    for (int m = 0; m < 4; ++m)
#pragma unroll
      for (int n = 0; n < 4; ++n)
        acc[m][n] = MFMA16(a[m], bfr[n], acc[m][n]);
    __syncthreads();
  }

#pragma unroll
  for (int m = 0; m < 4; ++m)
#pragma unroll
    for (int n = 0; n < 4; ++n)
#pragma unroll
      for (int r4 = 0; r4 < 4; ++r4) {
        int row = row0 + mw + m * 16 + (l >> 4) * 4 + r4;
        int col = col0 + nw + n * 16 + (l & 15);
        int bb = row >> 11, s = row & (SS - 1), h = col >> 6, d = col & (HD - 1);
        __hip_bfloat16 val = __float2bfloat16(acc[m][n][r4]);
        if (vmode) out[(((size_t)bb * NH + h) * HD + d) * SS + s] = val;
        else       out[(((size_t)bb * NH + h) * SS + s) * HD + d] = val;
      }
}

// ---- pass A: per-column denominators Zinv[k] = 1 / sum_{q>=k} exp(S/32) ----
__global__ __launch_bounds__(256) void k_cstat(const __hip_bfloat16* __restrict__ qb,
                                               const __hip_bfloat16* __restrict__ kb,
                                               float* __restrict__ zinv) {
  __shared__ __hip_bfloat16 Kt[64 * 64];
  __shared__ __hip_bfloat16 Qt[64 * 64];
  __shared__ float red[4][64];
  const int bh = blockIdx.x, k0 = blockIdx.y * 64;
  const int tid = threadIdx.x, w = tid >> 6, l = tid & 63;

#pragma unroll
  for (int i = 0; i < 2; ++i) {
    int c = w * 2 + i;
    int r = c * 8 + (l >> 3), cc = (l & 7) * 8;
    gl_lds16(kb + ((size_t)bh * SS + k0 + r) * HD + cc, &Kt[c * 512]);
  }

  float csum[4] = {0.f, 0.f, 0.f, 0.f};
  for (int q0 = k0; q0 < SS; q0 += 64) {
#pragma unroll
    for (int i = 0; i < 2; ++i) {
      int c = w * 2 + i;
      int r = c * 8 + (l >> 3), cc = (l & 7) * 8;
      gl_lds16(qb + ((size_t)bh * SS + q0 + r) * HD + cc, &Qt[c * 512]);
    }
    __syncthreads();
    short8 qa[2];
#pragma unroll
    for (int ks = 0; ks < 2; ++ks)
      qa[ks] = *(const short8*)&Qt[(w * 16 + (l & 15)) * HD + ks * 32 + (l >> 4) * 8];
#pragma unroll
    for (int n = 0; n < 4; ++n) {
      floatx4 s = {0.f, 0.f, 0.f, 0.f};
#pragma unroll
      for (int ks = 0; ks < 2; ++ks)
        s = MFMA16(qa[ks],
                   *(const short8*)&Kt[(n * 16 + (l & 15)) * HD + ks * 32 + (l >> 4) * 8], s);
#pragma unroll
      for (int r4 = 0; r4 < 4; ++r4) {
        int q = q0 + w * 16 + (l >> 4) * 4 + r4;
        int k = k0 + n * 16 + (l & 15);
        if (k <= q) csum[n] += __expf(s[r4] * SCALE);
      }
    }
    __syncthreads();
  }
#pragma unroll
  for (int n = 0; n < 4; ++n) {
    csum[n] += __shfl_xor(csum[n], 16);
    csum[n] += __shfl_xor(csum[n], 32);
    if (l < 16) red[w][n * 16 + l] = csum[n];
  }
  __syncthreads();
  if (tid < 64) {
    float z = red[0][tid] + red[1][tid] + red[2][tid] + red[3][tid];
    zinv[(size_t)bh * SS + k0 + tid] = 1.0f / z;
  }
}

// ---- pass B: ctx[q,:] = sum_{k<=q} exp(S/32)*Zinv[k]*V[k,:] ----
__global__ __launch_bounds__(256) void k_ctx(const __hip_bfloat16* __restrict__ qb,
                                             const __hip_bfloat16* __restrict__ kb,
                                             const __hip_bfloat16* __restrict__ vtb,
                                             const float* __restrict__ zinv,
                                             float* __restrict__ out) {
  __shared__ __hip_bfloat16 Qt[64 * 64];
  __shared__ __hip_bfloat16 Kt[64 * 64];
  __shared__ __hip_bfloat16 Vt[64 * 64];
  __shared__ __hip_bfloat16 Pt[4][16 * 64];
  __shared__ float zl[64];
  const int bh = blockIdx.x, bb = bh >> 4, h = bh & 15;
  const int q0 = (gridDim.y - 1 - blockIdx.y) * 64;  // big blocks first
  const int tid = threadIdx.x, w = tid >> 6, l = tid & 63;

#pragma unroll
  for (int i = 0; i < 2; ++i) {
    int c = w * 2 + i;
    int r = c * 8 + (l >> 3), cc = (l & 7) * 8;
    gl_lds16(qb + ((size_t)bh * SS + q0 + r) * HD + cc, &Qt[c * 512]);
  }
  __syncthreads();
  short8 qa[2];
#pragma unroll
  for (int ks = 0; ks < 2; ++ks)
    qa[ks] = *(const short8*)&Qt[(w * 16 + (l & 15)) * HD + ks * 32 + (l >> 4) * 8];

  const floatx4 fz = {0.f, 0.f, 0.f, 0.f};
  floatx4 acc[4];
#pragma unroll
  for (int i = 0; i < 4; ++i) acc[i] = fz;

  const int nkt = q0 / 64 + 1;
  for (int kt = 0; kt < nkt; ++kt) {
    int k0 = kt * 64;
#pragma unroll
    for (int i = 0; i < 2; ++i) {
      int c = w * 2 + i;
      int r = c * 8 + (l >> 3), cc = (l & 7) * 8;
      gl_lds16(kb + ((size_t)bh * SS + k0 + r) * HD + cc, &Kt[c * 512]);
      gl_lds16(vtb + ((size_t)bh * HD + r) * SS + k0 + cc, &Vt[c * 512]);
    }
    if (tid < 64) zl[tid] = zinv[(size_t)bh * SS + k0 + tid];
    __syncthreads();

#pragma unroll
    for (int n = 0; n < 4; ++n) {
      floatx4 s = {0.f, 0.f, 0.f, 0.f};
#pragma unroll
      for (int ks = 0; ks < 2; ++ks)
        s = MFMA16(qa[ks],
                   *(const short8*)&Kt[(n * 16 + (l & 15)) * HD + ks * 32 + (l >> 4) * 8], s);
      float zv = zl[n * 16 + (l & 15)];
#pragma unroll
      for (int r4 = 0; r4 < 4; ++r4) {
        int q = q0 + w * 16 + (l >> 4) * 4 + r4;
        int k = k0 + n * 16 + (l & 15);
        float p = (k <= q) ? __expf(s[r4] * SCALE) * zv : 0.0f;
        Pt[w][((l >> 4) * 4 + r4) * HD + n * 16 + (l & 15)] = __float2bfloat16(p);
      }
    }
    // P (LDS, wave-private) as A-operand; V[d][k] rows as B-operand
#pragma unroll
    for (int ks = 0; ks < 2; ++ks) {
      short8 pa = *(const short8*)&Pt[w][(l & 15) * HD + ks * 32 + (l >> 4) * 8];
#pragma unroll
      for (int dn = 0; dn < 4; ++dn)
        acc[dn] = MFMA16(pa,
                         *(const short8*)&Vt[(dn * 16 + (l & 15)) * HD + ks * 32 + (l >> 4) * 8],
                         acc[dn]);
    }
    __syncthreads();
  }

#pragma unroll
  for (int dn = 0; dn < 4; ++dn)
#pragma unroll
    for (int r4 = 0; r4 < 4; ++r4) {
      int q = q0 + w * 16 + (l >> 4) * 4 + r4;
      out[((size_t)bb * SS + q) * DOUT + h * HD + dn * 16 + (l & 15)] = acc[dn][r4];
    }
}

extern "C" void kernel_launch(void* const* d_in, const int* in_sizes, int n_in,
                              void* d_out, int out_size, void* d_ws, size_t ws_size,
                              hipStream_t stream) {
  const float* x  = (const float*)d_in[0];
  const float* Wq = (const float*)d_in[1];
  const float* Wk = (const float*)d_in[2];
  const float* Wv = (const float*)d_in[3];
  float* out = (float*)d_out;
  char* ws = (char*)d_ws;

  __hip_bfloat16* xb  = (__hip_bfloat16*)(ws);                   // 8 MB
  __hip_bfloat16* wtq = (__hip_bfloat16*)(ws + (8ull  << 20));   // 2 MB
  __hip_bfloat16* wtk = (__hip_bfloat16*)(ws + (10ull << 20));   // 2 MB
  __hip_bfloat16* wtv = (__hip_bfloat16*)(ws + (12ull << 20));   // 2 MB
  __hip_bfloat16* qb  = (__hip_bfloat16*)(ws + (14ull << 20));   // 8 MB [b][h][s][d]
  __hip_bfloat16* kb  = (__hip_bfloat16*)(ws + (22ull << 20));   // 8 MB [b][h][s][d]
  __hip_bfloat16* vtb = (__hip_bfloat16*)(ws + (30ull << 20));   // 8 MB [b][h][d][s]
  float* zinv         = (float*)(ws + (38ull << 20));            // 256 KB

  k_cvt_x<<<4096, 256, 0, stream>>>(x, xb);
  dim3 tb(32, 8);
  k_twb<<<dim3(32, 32), tb, 0, stream>>>(Wq, wtq);
  k_twb<<<dim3(32, 32), tb, 0, stream>>>(Wk, wtk);
  k_twb<<<dim3(32, 32), tb, 0, stream>>>(Wv, wtv);
  k_qkv<<<dim3(8, 32, 3), 256, 0, stream>>>(xb, wtq, wtk, wtv, qb, kb, vtb);
  k_cstat<<<dim3(32, 32), 256, 0, stream>>>(qb, kb, zinv);
  k_ctx<<<dim3(32, 32), 256, 0, stream>>>(qb, kb, vtb, zinv, out);
}

// Round 3
// 126.042 us; speedup vs baseline: 1.2033x; 1.2033x over previous
//
#include <hip/hip_runtime.h>
#include <hip/hip_bf16.h>

// CausalSelfAttention quirk kernel: softmax over QUERY axis, scale sqrt(D_OUT)=32.
// w[q,k] = exp(S/32)/Z[k], Z[k] = sum_{q>=k} exp(S/32)  (per-COLUMN denominator).
// Pass A (k_cstat) computes Z and folds 1/Z into V; pass B (k_ctx) recomputes S
// tile-wise and does PV. 1/32*log2e is folded into Q at the QKV epilogue so the
// inner loops use a bare exp2.
// NOTE: no local arrays of LDS pointers (gfx950 rejects addrspacecast static
// initializers) — double-buffer selection is done with offset arithmetic.

typedef __attribute__((ext_vector_type(8))) short short8;
typedef __attribute__((ext_vector_type(4))) float floatx4;

#define SS 2048
#define DIN 1024
#define DOUT 1024
#define NH 16
#define HD 64
#define QSCALE 0.04508422002778011f  // (1/32) * log2(e)

#define MFMA16(a,b,c) __builtin_amdgcn_mfma_f32_16x16x32_bf16((a),(b),(c),0,0,0)
#define EXP2F(x) __builtin_amdgcn_exp2f(x)

__device__ __forceinline__ void gl_lds16(const void* g, void* l) {
  __builtin_amdgcn_global_load_lds((const __attribute__((address_space(1))) void*)g,
                                   (__attribute__((address_space(3))) void*)l, 16, 0, 0);
}

// Stage an 8-row chunk `c` of a [*][64] bf16 tile (global row stride `stride` elems)
// into LDS at lds + c*512, linear dest (global_load_lds requirement). XOR-swizzle is
// applied on the GLOBAL source slot so that LDS[r][slot s] holds global slot s^(r&7).
__device__ __forceinline__ void stage64(const __hip_bfloat16* __restrict__ src, int stride,
                                        __hip_bfloat16* lds, int c, int l) {
  int r = c * 8 + (l >> 3);
  int cc = ((l & 7) ^ ((l >> 3) & 7)) * 8;
  gl_lds16(src + (size_t)r * stride + cc, lds + c * 512);
}

// Read a 16B MFMA fragment from a swizzled [*][64] tile: row `row`, k-slot ks*4+(l>>4).
__device__ __forceinline__ short8 frag64(const __hip_bfloat16* lds, int row, int ks, int l) {
  return *(const short8*)&lds[row * 64 + (((ks * 4 + (l >> 4)) ^ (row & 7)) * 8)];
}

// ---- convert x fp32 -> bf16 ----
__global__ __launch_bounds__(256) void k_cvt_x(const float* __restrict__ x,
                                               __hip_bfloat16* __restrict__ xb) {
  size_t i = ((size_t)blockIdx.x * 256 + threadIdx.x) * 4;
  float4 v = *(const float4*)(x + i);
  union { __hip_bfloat16 h[4]; short4 s; } u;
  u.h[0] = __float2bfloat16(v.x); u.h[1] = __float2bfloat16(v.y);
  u.h[2] = __float2bfloat16(v.z); u.h[3] = __float2bfloat16(v.w);
  *(short4*)(xb + i) = u.s;
}

// ---- transpose + convert W [k][c] fp32 -> Wt [c][k] bf16 ----
__global__ void k_twb(const float* __restrict__ W, __hip_bfloat16* __restrict__ Wt) {
  __shared__ float t[32][33];
  int tx = threadIdx.x, ty = threadIdx.y;
  int k0 = blockIdx.y * 32, c0 = blockIdx.x * 32;
#pragma unroll
  for (int i = 0; i < 4; ++i)
    t[ty + 8*i][tx] = W[(size_t)(k0 + ty + 8*i) * DOUT + c0 + tx];
  __syncthreads();
#pragma unroll
  for (int i = 0; i < 4; ++i)
    Wt[(size_t)(c0 + ty + 8*i) * DIN + k0 + tx] = __float2bfloat16(t[tx][ty + 8*i]);
}

// ---- QKV GEMM, BK=64, double-buffered, swizzled LDS.
// q (z=0, pre-scaled by QSCALE), k (z=1): [b][h][s][d] ; v (z=2): [b][h][d][s] ----
__global__ __launch_bounds__(256) void k_qkv(
    const __hip_bfloat16* __restrict__ xb,
    const __hip_bfloat16* __restrict__ wq, const __hip_bfloat16* __restrict__ wk,
    const __hip_bfloat16* __restrict__ wv,
    __hip_bfloat16* __restrict__ qb, __hip_bfloat16* __restrict__ kb,
    __hip_bfloat16* __restrict__ vb) {
  __shared__ __hip_bfloat16 smem[32768];  // A0|A1|B0|B1, 8192 elems each (64KB)

  const __hip_bfloat16* wt; __hip_bfloat16* outp;
  if (blockIdx.z == 0)      { wt = wq; outp = qb; }
  else if (blockIdx.z == 1) { wt = wk; outp = kb; }
  else                      { wt = wv; outp = vb; }

  const int tid = threadIdx.x, w = tid >> 6, l = tid & 63;
  const int row0 = blockIdx.y * 128, col0 = blockIdx.x * 128;
  const int mw = (w >> 1) * 64, nw = (w & 1) * 64;

  const floatx4 fz = {0.f, 0.f, 0.f, 0.f};
  floatx4 acc[4][4];
#pragma unroll
  for (int m = 0; m < 4; ++m)
#pragma unroll
    for (int n = 0; n < 4; ++n) acc[m][n] = fz;

#pragma unroll
  for (int i = 0; i < 4; ++i) {
    stage64(xb + (size_t)row0 * DIN, DIN, smem, w*4+i, l);
    stage64(wt + (size_t)col0 * DIN, DIN, smem + 16384, w*4+i, l);
  }
  __syncthreads();

  for (int kt = 0; kt < 16; ++kt) {
    int cur = kt & 1;
    __hip_bfloat16* Ac = smem + cur * 8192;
    __hip_bfloat16* Bc = smem + 16384 + cur * 8192;
    if (kt < 15) {
      int kk = (kt + 1) * 64;
      __hip_bfloat16* An = smem + (cur ^ 1) * 8192;
      __hip_bfloat16* Bn = smem + 16384 + (cur ^ 1) * 8192;
#pragma unroll
      for (int i = 0; i < 4; ++i) {
        stage64(xb + (size_t)row0 * DIN + kk, DIN, An, w*4+i, l);
        stage64(wt + (size_t)col0 * DIN + kk, DIN, Bn, w*4+i, l);
      }
    }
    short8 a[4][2], b[4][2];
#pragma unroll
    for (int m = 0; m < 4; ++m)
#pragma unroll
      for (int ks = 0; ks < 2; ++ks)
        a[m][ks] = frag64(Ac, mw + m*16 + (l & 15), ks, l);
#pragma unroll
    for (int n = 0; n < 4; ++n)
#pragma unroll
      for (int ks = 0; ks < 2; ++ks)
        b[n][ks] = frag64(Bc, nw + n*16 + (l & 15), ks, l);
#pragma unroll
    for (int ks = 0; ks < 2; ++ks)
#pragma unroll
      for (int m = 0; m < 4; ++m)
#pragma unroll
        for (int n = 0; n < 4; ++n)
          acc[m][n] = MFMA16(a[m][ks], b[n][ks], acc[m][n]);
    __syncthreads();
  }

  if (blockIdx.z == 2) {
    // V: transpose through LDS (padded stride 136), then 16B coalesced stores.
    __hip_bfloat16* Vt2 = smem;  // 128 x 136 = 34816B, aliases staging (all waves sync'd)
#pragma unroll
    for (int m = 0; m < 4; ++m)
#pragma unroll
      for (int n = 0; n < 4; ++n)
#pragma unroll
        for (int r4 = 0; r4 < 4; ++r4) {
          int r = mw + m*16 + ((l >> 4) << 2) + r4;   // s-index in tile
          int c = nw + n*16 + (l & 15);               // col (head-dim) in tile
          Vt2[c * 136 + r] = __float2bfloat16(acc[m][n][r4]);
        }
    __syncthreads();
    int bb2 = row0 >> 11, sbase = row0 & (SS - 1);
#pragma unroll
    for (int i = 0; i < 8; ++i) {
      int drow = (tid >> 4) + i * 16;       // 0..127 col index
      int scol = (tid & 15) * 8;            // 0..120 s index
      int colg = col0 + drow, hh = colg >> 6, d = colg & 63;
      *(short8*)(outp + (((size_t)bb2 * NH + hh) * HD + d) * SS + sbase + scol) =
          *(const short8*)&Vt2[drow * 136 + scol];
    }
  } else {
    float sc = (blockIdx.z == 0) ? QSCALE : 1.0f;
#pragma unroll
    for (int m = 0; m < 4; ++m)
#pragma unroll
      for (int n = 0; n < 4; ++n)
#pragma unroll
        for (int r4 = 0; r4 < 4; ++r4) {
          int row = row0 + mw + m*16 + ((l >> 4) << 2) + r4;
          int col = col0 + nw + n*16 + (l & 15);
          int bb2 = row >> 11, s = row & (SS - 1), hh = col >> 6, d = col & 63;
          outp[(((size_t)bb2 * NH + hh) * SS + s) * HD + d] =
              __float2bfloat16(acc[m][n][r4] * sc);
        }
  }
}

// ---- pass A: Z[k] = sum_{q>=k} exp2(S'), then scale V columns by 1/Z in place.
// Each block handles k-tiles j=by and 31-by (uniform total work). ----
__global__ __launch_bounds__(256) void k_cstat(const __hip_bfloat16* __restrict__ qb,
                                               const __hip_bfloat16* __restrict__ kb,
                                               __hip_bfloat16* __restrict__ vtb) {
  __shared__ __hip_bfloat16 smem[20480];  // Kt 4096 | Qt0 8192 | Qt1 8192 (40KB)
  __shared__ float red[4][64];
  __shared__ float zl[64];
  __hip_bfloat16* Kt = smem;
  const int bh = blockIdx.x;
  const int tid = threadIdx.x, w = tid >> 6, l = tid & 63;

  for (int jj = 0; jj < 2; ++jj) {
    int j = jj ? (31 - (int)blockIdx.y) : (int)blockIdx.y;
    int k0 = j * 64;
    int t0 = k0 >> 7, niter = 16 - t0;

#pragma unroll
    for (int i = 0; i < 2; ++i)
      stage64(kb + ((size_t)bh * SS + k0) * HD, HD, Kt, w*2+i, l);
#pragma unroll
    for (int i = 0; i < 4; ++i)
      stage64(qb + ((size_t)bh * SS + (t0 << 7)) * HD, HD, smem + 4096, w*4+i, l);
    __syncthreads();

    short8 kf[4][2];
#pragma unroll
    for (int n = 0; n < 4; ++n)
#pragma unroll
      for (int ks = 0; ks < 2; ++ks)
        kf[n][ks] = frag64(Kt, n*16 + (l & 15), ks, l);

    float csum[4] = {0.f, 0.f, 0.f, 0.f};
    for (int it = 0; it < niter; ++it) {
      int cur = it & 1;
      __hip_bfloat16* Qc = smem + 4096 + cur * 8192;
      int q0 = (t0 + it) << 7;
      if (it + 1 < niter) {
        __hip_bfloat16* Qn = smem + 4096 + (cur ^ 1) * 8192;
#pragma unroll
        for (int i = 0; i < 4; ++i)
          stage64(qb + ((size_t)bh * SS + q0 + 128) * HD, HD, Qn, w*4+i, l);
      }
      int qw = q0 + w * 32;
      if (qw + 31 >= k0) {
        short8 qa[2][2];
#pragma unroll
        for (int mm = 0; mm < 2; ++mm)
#pragma unroll
          for (int ks = 0; ks < 2; ++ks)
            qa[mm][ks] = frag64(Qc, w*32 + mm*16 + (l & 15), ks, l);
        floatx4 s[2][4];
#pragma unroll
        for (int mm = 0; mm < 2; ++mm)
#pragma unroll
          for (int n = 0; n < 4; ++n) {
            floatx4 t = {0.f, 0.f, 0.f, 0.f};
#pragma unroll
            for (int ks = 0; ks < 2; ++ks) t = MFMA16(qa[mm][ks], kf[n][ks], t);
            s[mm][n] = t;
          }
        bool dia = (k0 + 63 > qw);
#pragma unroll
        for (int mm = 0; mm < 2; ++mm)
#pragma unroll
          for (int n = 0; n < 4; ++n)
#pragma unroll
            for (int r4 = 0; r4 < 4; ++r4) {
              float e = EXP2F(s[mm][n][r4]);
              if (dia) {
                int q = qw + mm*16 + ((l >> 4) << 2) + r4;
                int k = k0 + n*16 + (l & 15);
                if (k > q) e = 0.f;
              }
              csum[n] += e;
            }
      }
      __syncthreads();
    }

#pragma unroll
    for (int n = 0; n < 4; ++n) {
      csum[n] += __shfl_xor(csum[n], 16);
      csum[n] += __shfl_xor(csum[n], 32);
      if (l < 16) red[w][n*16 + l] = csum[n];
    }
    __syncthreads();
    if (tid < 64)
      zl[tid] = 1.0f / (red[0][tid] + red[1][tid] + red[2][tid] + red[3][tid]);
    __syncthreads();
    // scale vtb columns [k0, k0+64) by 1/Z (in place; disjoint per block/job)
#pragma unroll
    for (int i = 0; i < 4; ++i) {
      int d = (tid >> 4) + i * 16;
      int c = (tid & 15) * 4;
      size_t base = ((size_t)bh * HD + d) * SS + k0 + c;
      short4 v = *(const short4*)(vtb + base);
      __hip_bfloat16* hp = (__hip_bfloat16*)&v;
#pragma unroll
      for (int jv = 0; jv < 4; ++jv)
        hp[jv] = __float2bfloat16(__bfloat162float(hp[jv]) * zl[c + jv]);
      *(short4*)(vtb + base) = v;
    }
    __syncthreads();
  }
}

// ---- pass B: ctx[q,:] = sum_{k<=q} exp2(S') * Vs[k,:]  (Vs already has 1/Z) ----
__global__ __launch_bounds__(256) void k_ctx(const __hip_bfloat16* __restrict__ qb,
                                             const __hip_bfloat16* __restrict__ kb,
                                             const __hip_bfloat16* __restrict__ vtb,
                                             float* __restrict__ outp) {
  __shared__ __hip_bfloat16 smem[24576];  // Qt/Pt 8192 | K0 4096 | V0 4096 | K1 4096 | V1 4096
  __hip_bfloat16* Qt = smem;
  const int bh = blockIdx.x, bb = bh >> 4, h = bh & 15;
  int by = blockIdx.y;
  int T = (by < 8) ? (15 - by) : (by - 8);   // pairs big+small across dispatch rounds
  int q0 = T * 128;
  const int tid = threadIdx.x, w = tid >> 6, l = tid & 63;

#pragma unroll
  for (int i = 0; i < 4; ++i)
    stage64(qb + ((size_t)bh * SS + q0) * HD, HD, Qt, w*4+i, l);
#pragma unroll
  for (int i = 0; i < 2; ++i) {
    stage64(kb + (size_t)bh * SS * HD, HD, smem + 8192, w*2+i, l);
    stage64(vtb + (size_t)bh * HD * SS, SS, smem + 12288, w*2+i, l);
  }
  __syncthreads();
  short8 qa[2][2];
#pragma unroll
  for (int mm = 0; mm < 2; ++mm)
#pragma unroll
    for (int ks = 0; ks < 2; ++ks)
      qa[mm][ks] = frag64(Qt, w*32 + mm*16 + (l & 15), ks, l);
  __syncthreads();  // Qt now dead; Pt aliases it below
  __hip_bfloat16* Pt = smem + w * 2048;  // wave-private 32x64

  const floatx4 fz = {0.f, 0.f, 0.f, 0.f};
  floatx4 acc[2][4];
#pragma unroll
  for (int mm = 0; mm < 2; ++mm)
#pragma unroll
    for (int dn = 0; dn < 4; ++dn) acc[mm][dn] = fz;

  int nkt = (q0 >> 6) + 2;
  int qw = q0 + w * 32;
  for (int kt = 0; kt < nkt; ++kt) {
    int cur = kt & 1;
    __hip_bfloat16* Kc = smem + 8192 + cur * 8192;
    __hip_bfloat16* Vc = smem + 12288 + cur * 8192;
    int k0 = kt << 6;
    if (kt + 1 < nkt) {
      int kn = k0 + 64;
      __hip_bfloat16* Kn = smem + 8192 + (cur ^ 1) * 8192;
      __hip_bfloat16* Vn = smem + 12288 + (cur ^ 1) * 8192;
#pragma unroll
      for (int i = 0; i < 2; ++i) {
        stage64(kb + ((size_t)bh * SS + kn) * HD, HD, Kn, w*2+i, l);
        stage64(vtb + (size_t)bh * HD * SS + kn, SS, Vn, w*2+i, l);
      }
    }
    if (k0 < qw + 32) {   // wave has unmasked elements in this k-tile
      floatx4 s[2][4];
#pragma unroll
      for (int mm = 0; mm < 2; ++mm)
#pragma unroll
        for (int n = 0; n < 4; ++n) {
          floatx4 t = {0.f, 0.f, 0.f, 0.f};
#pragma unroll
          for (int ks = 0; ks < 2; ++ks)
            t = MFMA16(qa[mm][ks], frag64(Kc, n*16 + (l & 15), ks, l), t);
          s[mm][n] = t;
        }
      bool dia = (k0 + 63 > qw);
#pragma unroll
      for (int mm = 0; mm < 2; ++mm)
#pragma unroll
        for (int n = 0; n < 4; ++n)
#pragma unroll
          for (int r4 = 0; r4 < 4; ++r4) {
            float p = EXP2F(s[mm][n][r4]);
            if (dia) {
              int q = qw + mm*16 + ((l >> 4) << 2) + r4;
              int k = k0 + n*16 + (l & 15);
              if (k > q) p = 0.f;
            }
            int rl = mm*16 + ((l >> 4) << 2) + r4;   // 0..31
            Pt[rl * 64 + ((n*16 + (l & 15)) ^ ((rl & 7) << 3))] = __float2bfloat16(p);
          }
#pragma unroll
      for (int mm = 0; mm < 2; ++mm)
#pragma unroll
        for (int ks = 0; ks < 2; ++ks) {
          short8 pa = frag64(Pt, mm*16 + (l & 15), ks, l);
#pragma unroll
          for (int dn = 0; dn < 4; ++dn)
            acc[mm][dn] = MFMA16(pa, frag64(Vc, dn*16 + (l & 15), ks, l), acc[mm][dn]);
        }
    }
    __syncthreads();
  }

#pragma unroll
  for (int mm = 0; mm < 2; ++mm)
#pragma unroll
    for (int dn = 0; dn < 4; ++dn)
#pragma unroll
      for (int r4 = 0; r4 < 4; ++r4) {
        int q = qw + mm*16 + ((l >> 4) << 2) + r4;
        outp[((size_t)bb * SS + q) * DOUT + h * HD + dn*16 + (l & 15)] = acc[mm][dn][r4];
      }
}

extern "C" void kernel_launch(void* const* d_in, const int* in_sizes, int n_in,
                              void* d_out, int out_size, void* d_ws, size_t ws_size,
                              hipStream_t stream) {
  const float* x  = (const float*)d_in[0];
  const float* Wq = (const float*)d_in[1];
  const float* Wk = (const float*)d_in[2];
  const float* Wv = (const float*)d_in[3];
  float* out = (float*)d_out;
  char* ws = (char*)d_ws;

  __hip_bfloat16* xb  = (__hip_bfloat16*)(ws);                   // 8 MB
  __hip_bfloat16* wtq = (__hip_bfloat16*)(ws + (8ull  << 20));   // 2 MB
  __hip_bfloat16* wtk = (__hip_bfloat16*)(ws + (10ull << 20));   // 2 MB
  __hip_bfloat16* wtv = (__hip_bfloat16*)(ws + (12ull << 20));   // 2 MB
  __hip_bfloat16* qb  = (__hip_bfloat16*)(ws + (14ull << 20));   // 8 MB [b][h][s][d], pre-scaled
  __hip_bfloat16* kb  = (__hip_bfloat16*)(ws + (22ull << 20));   // 8 MB [b][h][s][d]
  __hip_bfloat16* vtb = (__hip_bfloat16*)(ws + (30ull << 20));   // 8 MB [b][h][d][s], 1/Z folded

  k_cvt_x<<<4096, 256, 0, stream>>>(x, xb);
  dim3 tb(32, 8);
  k_twb<<<dim3(32, 32), tb, 0, stream>>>(Wq, wtq);
  k_twb<<<dim3(32, 32), tb, 0, stream>>>(Wk, wtk);
  k_twb<<<dim3(32, 32), tb, 0, stream>>>(Wv, wtv);
  k_qkv<<<dim3(8, 32, 3), 256, 0, stream>>>(xb, wtq, wtk, wtv, qb, kb, vtb);
  k_cstat<<<dim3(32, 16), 256, 0, stream>>>(qb, kb, vtb);
  k_ctx<<<dim3(32, 16), 256, 0, stream>>>(qb, kb, vtb, out);
}

// Round 4
// 118.974 us; speedup vs baseline: 1.2748x; 1.0594x over previous
//
#include <hip/hip_runtime.h>
#include <hip/hip_bf16.h>

// CausalSelfAttention quirk kernel: softmax over QUERY axis, scale sqrt(D_OUT)=32.
// w[q,k] = exp(S/32)/Z[k], Z[k] = sum_{q>=k} exp(S/32)  (per-COLUMN denominator).
// Pass A (k_cstat) computes Z and folds 1/Z into V; pass B (k_ctx) recomputes S
// tile-wise and does PV. 1/32*log2e is folded into Q at the QKV epilogue so the
// inner loops use a bare exp2.
// k_ctx: 8-wave blocks; waves 0-3 own q-tile (15-by), waves 4-7 own q-tile (by).
// Each SIMD hosts one big + one small wave -> uniform 34 k-tiles/SIMD, and K/V
// staging is shared by both q-tiles.

typedef __attribute__((ext_vector_type(8))) short short8;
typedef __attribute__((ext_vector_type(4))) float floatx4;

#define SS 2048
#define DIN 1024
#define DOUT 1024
#define NH 16
#define HD 64
#define QSCALE 0.04508422002778011f  // (1/32) * log2(e)

#define MFMA16(a,b,c) __builtin_amdgcn_mfma_f32_16x16x32_bf16((a),(b),(c),0,0,0)
#define EXP2F(x) __builtin_amdgcn_exp2f(x)

__device__ __forceinline__ void gl_lds16(const void* g, void* l) {
  __builtin_amdgcn_global_load_lds((const __attribute__((address_space(1))) void*)g,
                                   (__attribute__((address_space(3))) void*)l, 16, 0, 0);
}

// Stage an 8-row chunk `c` of a [*][64] bf16 tile (global row stride `stride` elems)
// into LDS at lds + c*512, linear dest (global_load_lds requirement). XOR-swizzle is
// applied on the GLOBAL source slot so that LDS[r][slot s] holds global slot s^(r&7).
__device__ __forceinline__ void stage64(const __hip_bfloat16* __restrict__ src, int stride,
                                        __hip_bfloat16* lds, int c, int l) {
  int r = c * 8 + (l >> 3);
  int cc = ((l & 7) ^ ((l >> 3) & 7)) * 8;
  gl_lds16(src + (size_t)r * stride + cc, lds + c * 512);
}

// Read a 16B MFMA fragment from a swizzled [*][64] tile: row `row`, k-slot ks*4+(l>>4).
__device__ __forceinline__ short8 frag64(const __hip_bfloat16* lds, int row, int ks, int l) {
  return *(const short8*)&lds[row * 64 + (((ks * 4 + (l >> 4)) ^ (row & 7)) * 8)];
}

// ---- convert x fp32 -> bf16 ----
__global__ __launch_bounds__(256) void k_cvt_x(const float* __restrict__ x,
                                               __hip_bfloat16* __restrict__ xb) {
  size_t i = ((size_t)blockIdx.x * 256 + threadIdx.x) * 4;
  float4 v = *(const float4*)(x + i);
  union { __hip_bfloat16 h[4]; short4 s; } u;
  u.h[0] = __float2bfloat16(v.x); u.h[1] = __float2bfloat16(v.y);
  u.h[2] = __float2bfloat16(v.z); u.h[3] = __float2bfloat16(v.w);
  *(short4*)(xb + i) = u.s;
}

// ---- transpose + convert W [k][c] fp32 -> Wt [c][k] bf16 ----
__global__ void k_twb(const float* __restrict__ W, __hip_bfloat16* __restrict__ Wt) {
  __shared__ float t[32][33];
  int tx = threadIdx.x, ty = threadIdx.y;
  int k0 = blockIdx.y * 32, c0 = blockIdx.x * 32;
#pragma unroll
  for (int i = 0; i < 4; ++i)
    t[ty + 8*i][tx] = W[(size_t)(k0 + ty + 8*i) * DOUT + c0 + tx];
  __syncthreads();
#pragma unroll
  for (int i = 0; i < 4; ++i)
    Wt[(size_t)(c0 + ty + 8*i) * DIN + k0 + tx] = __float2bfloat16(t[tx][ty + 8*i]);
}

// ---- QKV GEMM, BK=64, double-buffered, swizzled LDS.
// q (z=0, pre-scaled by QSCALE), k (z=1): [b][h][s][d] ; v (z=2): [b][h][d][s] ----
__global__ __launch_bounds__(256) void k_qkv(
    const __hip_bfloat16* __restrict__ xb,
    const __hip_bfloat16* __restrict__ wq, const __hip_bfloat16* __restrict__ wk,
    const __hip_bfloat16* __restrict__ wv,
    __hip_bfloat16* __restrict__ qb, __hip_bfloat16* __restrict__ kb,
    __hip_bfloat16* __restrict__ vb) {
  __shared__ __hip_bfloat16 smem[32768];  // A0|A1|B0|B1, 8192 elems each (64KB)

  const __hip_bfloat16* wt; __hip_bfloat16* outp;
  if (blockIdx.z == 0)      { wt = wq; outp = qb; }
  else if (blockIdx.z == 1) { wt = wk; outp = kb; }
  else                      { wt = wv; outp = vb; }

  const int tid = threadIdx.x, w = tid >> 6, l = tid & 63;
  const int row0 = blockIdx.y * 128, col0 = blockIdx.x * 128;
  const int mw = (w >> 1) * 64, nw = (w & 1) * 64;

  const floatx4 fz = {0.f, 0.f, 0.f, 0.f};
  floatx4 acc[4][4];
#pragma unroll
  for (int m = 0; m < 4; ++m)
#pragma unroll
    for (int n = 0; n < 4; ++n) acc[m][n] = fz;

#pragma unroll
  for (int i = 0; i < 4; ++i) {
    stage64(xb + (size_t)row0 * DIN, DIN, smem, w*4+i, l);
    stage64(wt + (size_t)col0 * DIN, DIN, smem + 16384, w*4+i, l);
  }
  __syncthreads();

  for (int kt = 0; kt < 16; ++kt) {
    int cur = kt & 1;
    __hip_bfloat16* Ac = smem + cur * 8192;
    __hip_bfloat16* Bc = smem + 16384 + cur * 8192;
    if (kt < 15) {
      int kk = (kt + 1) * 64;
      __hip_bfloat16* An = smem + (cur ^ 1) * 8192;
      __hip_bfloat16* Bn = smem + 16384 + (cur ^ 1) * 8192;
#pragma unroll
      for (int i = 0; i < 4; ++i) {
        stage64(xb + (size_t)row0 * DIN + kk, DIN, An, w*4+i, l);
        stage64(wt + (size_t)col0 * DIN + kk, DIN, Bn, w*4+i, l);
      }
    }
    short8 a[4][2], b[4][2];
#pragma unroll
    for (int m = 0; m < 4; ++m)
#pragma unroll
      for (int ks = 0; ks < 2; ++ks)
        a[m][ks] = frag64(Ac, mw + m*16 + (l & 15), ks, l);
#pragma unroll
    for (int n = 0; n < 4; ++n)
#pragma unroll
      for (int ks = 0; ks < 2; ++ks)
        b[n][ks] = frag64(Bc, nw + n*16 + (l & 15), ks, l);
#pragma unroll
    for (int ks = 0; ks < 2; ++ks)
#pragma unroll
      for (int m = 0; m < 4; ++m)
#pragma unroll
        for (int n = 0; n < 4; ++n)
          acc[m][n] = MFMA16(a[m][ks], b[n][ks], acc[m][n]);
    __syncthreads();
  }

  if (blockIdx.z == 2) {
    // V: transpose through LDS (padded stride 136), then 16B coalesced stores.
    __hip_bfloat16* Vt2 = smem;  // 128 x 136 = 34816B, aliases staging (all waves sync'd)
#pragma unroll
    for (int m = 0; m < 4; ++m)
#pragma unroll
      for (int n = 0; n < 4; ++n)
#pragma unroll
        for (int r4 = 0; r4 < 4; ++r4) {
          int r = mw + m*16 + ((l >> 4) << 2) + r4;   // s-index in tile
          int c = nw + n*16 + (l & 15);               // col (head-dim) in tile
          Vt2[c * 136 + r] = __float2bfloat16(acc[m][n][r4]);
        }
    __syncthreads();
    int bb2 = row0 >> 11, sbase = row0 & (SS - 1);
#pragma unroll
    for (int i = 0; i < 8; ++i) {
      int drow = (tid >> 4) + i * 16;       // 0..127 col index
      int scol = (tid & 15) * 8;            // 0..120 s index
      int colg = col0 + drow, hh = colg >> 6, d = colg & 63;
      *(short8*)(outp + (((size_t)bb2 * NH + hh) * HD + d) * SS + sbase + scol) =
          *(const short8*)&Vt2[drow * 136 + scol];
    }
  } else {
    float sc = (blockIdx.z == 0) ? QSCALE : 1.0f;
#pragma unroll
    for (int m = 0; m < 4; ++m)
#pragma unroll
      for (int n = 0; n < 4; ++n)
#pragma unroll
        for (int r4 = 0; r4 < 4; ++r4) {
          int row = row0 + mw + m*16 + ((l >> 4) << 2) + r4;
          int col = col0 + nw + n*16 + (l & 15);
          int bb2 = row >> 11, s = row & (SS - 1), hh = col >> 6, d = col & 63;
          outp[(((size_t)bb2 * NH + hh) * SS + s) * HD + d] =
              __float2bfloat16(acc[m][n][r4] * sc);
        }
  }
}

// ---- pass A: Z[k] = sum_{q>=k} exp2(S'), then scale V columns by 1/Z in place.
// Each block handles k-tiles j=by and 31-by (uniform total work). ----
__global__ __launch_bounds__(256) void k_cstat(const __hip_bfloat16* __restrict__ qb,
                                               const __hip_bfloat16* __restrict__ kb,
                                               __hip_bfloat16* __restrict__ vtb) {
  __shared__ __hip_bfloat16 smem[20480];  // Kt 4096 | Qt0 8192 | Qt1 8192 (40KB)
  __shared__ float red[4][64];
  __shared__ float zl[64];
  __hip_bfloat16* Kt = smem;
  const int bh = blockIdx.x;
  const int tid = threadIdx.x, w = tid >> 6, l = tid & 63;

  for (int jj = 0; jj < 2; ++jj) {
    int j = jj ? (31 - (int)blockIdx.y) : (int)blockIdx.y;
    int k0 = j * 64;
    int t0 = k0 >> 7, niter = 16 - t0;

#pragma unroll
    for (int i = 0; i < 2; ++i)
      stage64(kb + ((size_t)bh * SS + k0) * HD, HD, Kt, w*2+i, l);
#pragma unroll
    for (int i = 0; i < 4; ++i)
      stage64(qb + ((size_t)bh * SS + (t0 << 7)) * HD, HD, smem + 4096, w*4+i, l);
    __syncthreads();

    short8 kf[4][2];
#pragma unroll
    for (int n = 0; n < 4; ++n)
#pragma unroll
      for (int ks = 0; ks < 2; ++ks)
        kf[n][ks] = frag64(Kt, n*16 + (l & 15), ks, l);

    float csum[4] = {0.f, 0.f, 0.f, 0.f};
    for (int it = 0; it < niter; ++it) {
      int cur = it & 1;
      __hip_bfloat16* Qc = smem + 4096 + cur * 8192;
      int q0 = (t0 + it) << 7;
      if (it + 1 < niter) {
        __hip_bfloat16* Qn = smem + 4096 + (cur ^ 1) * 8192;
#pragma unroll
        for (int i = 0; i < 4; ++i)
          stage64(qb + ((size_t)bh * SS + q0 + 128) * HD, HD, Qn, w*4+i, l);
      }
      int qw = q0 + w * 32;
      if (qw + 31 >= k0) {
        short8 qa[2][2];
#pragma unroll
        for (int mm = 0; mm < 2; ++mm)
#pragma unroll
          for (int ks = 0; ks < 2; ++ks)
            qa[mm][ks] = frag64(Qc, w*32 + mm*16 + (l & 15), ks, l);
        floatx4 s[2][4];
#pragma unroll
        for (int mm = 0; mm < 2; ++mm)
#pragma unroll
          for (int n = 0; n < 4; ++n) {
            floatx4 t = {0.f, 0.f, 0.f, 0.f};
#pragma unroll
            for (int ks = 0; ks < 2; ++ks) t = MFMA16(qa[mm][ks], kf[n][ks], t);
            s[mm][n] = t;
          }
        bool dia = (k0 + 63 > qw);
#pragma unroll
        for (int mm = 0; mm < 2; ++mm)
#pragma unroll
          for (int n = 0; n < 4; ++n)
#pragma unroll
            for (int r4 = 0; r4 < 4; ++r4) {
              float e = EXP2F(s[mm][n][r4]);
              if (dia) {
                int q = qw + mm*16 + ((l >> 4) << 2) + r4;
                int k = k0 + n*16 + (l & 15);
                if (k > q) e = 0.f;
              }
              csum[n] += e;
            }
      }
      __syncthreads();
    }

#pragma unroll
    for (int n = 0; n < 4; ++n) {
      csum[n] += __shfl_xor(csum[n], 16);
      csum[n] += __shfl_xor(csum[n], 32);
      if (l < 16) red[w][n*16 + l] = csum[n];
    }
    __syncthreads();
    if (tid < 64)
      zl[tid] = 1.0f / (red[0][tid] + red[1][tid] + red[2][tid] + red[3][tid]);
    __syncthreads();
    // scale vtb columns [k0, k0+64) by 1/Z (in place; disjoint per block/job)
#pragma unroll
    for (int i = 0; i < 4; ++i) {
      int d = (tid >> 4) + i * 16;
      int c = (tid & 15) * 4;
      size_t base = ((size_t)bh * HD + d) * SS + k0 + c;
      short4 v = *(const short4*)(vtb + base);
      __hip_bfloat16* hp = (__hip_bfloat16*)&v;
#pragma unroll
      for (int jv = 0; jv < 4; ++jv)
        hp[jv] = __float2bfloat16(__bfloat162float(hp[jv]) * zl[c + jv]);
      *(short4*)(vtb + base) = v;
    }
    __syncthreads();
  }
}

// ---- pass B: ctx[q,:] = sum_{k<=q} exp2(S') * Vs[k,:]  (Vs already has 1/Z).
// 8 waves: waves 0-3 own q-tile (15-by) [big], waves 4-7 own q-tile (by) [small].
// One K/V stage per k-step shared by both tiles; per-SIMD work uniform (34 k-tiles).
// LDS (bf16 elems): Q/P 0..16383 (Qbig 0..8191, Qsml 8192..16383; Pt wave w at
// w*2048 after Q frags consumed) | K dbuf 16384+cur*4096 | V dbuf 24576+cur*4096.
__global__ __launch_bounds__(512) void k_ctx(const __hip_bfloat16* __restrict__ qb,
                                             const __hip_bfloat16* __restrict__ kb,
                                             const __hip_bfloat16* __restrict__ vtb,
                                             float* __restrict__ outp) {
  __shared__ __hip_bfloat16 smem[32768];  // 64KB
  const int bh = blockIdx.x, bb = bh >> 4, h = bh & 15;
  const int by = blockIdx.y;
  const int tid = threadIdx.x, w = tid >> 6, l = tid & 63;
  const int Tbig = 15 - by, Tsml = by;
  const int myT = (w < 4) ? Tbig : Tsml;
  const int q0 = myT * 128;
  const int qw = q0 + (w & 3) * 32;
  const int nkt = Tbig * 2 + 2;   // big tile's causal k-range covers small's

  // stage both Q tiles (16 chunks each; 2 per wave per tile) + K0/V0 (1 chunk/wave)
#pragma unroll
  for (int i = 0; i < 2; ++i) {
    stage64(qb + ((size_t)bh * SS + Tbig * 128) * HD, HD, smem,        w*2+i, l);
    stage64(qb + ((size_t)bh * SS + Tsml * 128) * HD, HD, smem + 8192, w*2+i, l);
  }
  stage64(kb + (size_t)bh * SS * HD, HD, smem + 16384, w, l);
  stage64(vtb + (size_t)bh * HD * SS, SS, smem + 24576, w, l);
  __syncthreads();

  short8 qa[2][2];
  {
    const __hip_bfloat16* Qt = smem + ((w < 4) ? 0 : 8192);
#pragma unroll
    for (int mm = 0; mm < 2; ++mm)
#pragma unroll
      for (int ks = 0; ks < 2; ++ks)
        qa[mm][ks] = frag64(Qt, (w & 3)*32 + mm*16 + (l & 15), ks, l);
  }
  __syncthreads();  // Q region now dead; Pt aliases it below
  __hip_bfloat16* Pt = smem + w * 2048;  // wave-private 32x64

  const floatx4 fz = {0.f, 0.f, 0.f, 0.f};
  floatx4 acc[2][4];
#pragma unroll
  for (int mm = 0; mm < 2; ++mm)
#pragma unroll
    for (int dn = 0; dn < 4; ++dn) acc[mm][dn] = fz;

  for (int kt = 0; kt < nkt; ++kt) {
    int cur = kt & 1;
    __hip_bfloat16* Kc = smem + 16384 + cur * 4096;
    __hip_bfloat16* Vc = smem + 24576 + cur * 4096;
    int k0 = kt << 6;
    if (kt + 1 < nkt) {
      int kn = k0 + 64;
      stage64(kb + ((size_t)bh * SS + kn) * HD, HD, smem + 16384 + (cur^1) * 4096, w, l);
      stage64(vtb + (size_t)bh * HD * SS + kn, SS, smem + 24576 + (cur^1) * 4096, w, l);
    }
    if (k0 < qw + 32) {   // wave has unmasked elements in this k-tile
      floatx4 s[2][4];
#pragma unroll
      for (int mm = 0; mm < 2; ++mm)
#pragma unroll
        for (int n = 0; n < 4; ++n) {
          floatx4 t = {0.f, 0.f, 0.f, 0.f};
#pragma unroll
          for (int ks = 0; ks < 2; ++ks)
            t = MFMA16(qa[mm][ks], frag64(Kc, n*16 + (l & 15), ks, l), t);
          s[mm][n] = t;
        }
      bool dia = (k0 + 63 > qw);
#pragma unroll
      for (int mm = 0; mm < 2; ++mm)
#pragma unroll
        for (int n = 0; n < 4; ++n)
#pragma unroll
          for (int r4 = 0; r4 < 4; ++r4) {
            float p = EXP2F(s[mm][n][r4]);
            if (dia) {
              int q = qw + mm*16 + ((l >> 4) << 2) + r4;
              int k = k0 + n*16 + (l & 15);
              if (k > q) p = 0.f;
            }
            int rl = mm*16 + ((l >> 4) << 2) + r4;   // 0..31
            Pt[rl * 64 + ((n*16 + (l & 15)) ^ ((rl & 7) << 3))] = __float2bfloat16(p);
          }
#pragma unroll
      for (int mm = 0; mm < 2; ++mm)
#pragma unroll
        for (int ks = 0; ks < 2; ++ks) {
          short8 pa = frag64(Pt, mm*16 + (l & 15), ks, l);
#pragma unroll
          for (int dn = 0; dn < 4; ++dn)
            acc[mm][dn] = MFMA16(pa, frag64(Vc, dn*16 + (l & 15), ks, l), acc[mm][dn]);
        }
    }
    __syncthreads();
  }

#pragma unroll
  for (int mm = 0; mm < 2; ++mm)
#pragma unroll
    for (int dn = 0; dn < 4; ++dn)
#pragma unroll
      for (int r4 = 0; r4 < 4; ++r4) {
        int q = qw + mm*16 + ((l >> 4) << 2) + r4;
        outp[((size_t)bb * SS + q) * DOUT + h * HD + dn*16 + (l & 15)] = acc[mm][dn][r4];
      }
}

extern "C" void kernel_launch(void* const* d_in, const int* in_sizes, int n_in,
                              void* d_out, int out_size, void* d_ws, size_t ws_size,
                              hipStream_t stream) {
  const float* x  = (const float*)d_in[0];
  const float* Wq = (const float*)d_in[1];
  const float* Wk = (const float*)d_in[2];
  const float* Wv = (const float*)d_in[3];
  float* out = (float*)d_out;
  char* ws = (char*)d_ws;

  __hip_bfloat16* xb  = (__hip_bfloat16*)(ws);                   // 8 MB
  __hip_bfloat16* wtq = (__hip_bfloat16*)(ws + (8ull  << 20));   // 2 MB
  __hip_bfloat16* wtk = (__hip_bfloat16*)(ws + (10ull << 20));   // 2 MB
  __hip_bfloat16* wtv = (__hip_bfloat16*)(ws + (12ull << 20));   // 2 MB
  __hip_bfloat16* qb  = (__hip_bfloat16*)(ws + (14ull << 20));   // 8 MB [b][h][s][d], pre-scaled
  __hip_bfloat16* kb  = (__hip_bfloat16*)(ws + (22ull << 20));   // 8 MB [b][h][s][d]
  __hip_bfloat16* vtb = (__hip_bfloat16*)(ws + (30ull << 20));   // 8 MB [b][h][d][s], 1/Z folded

  k_cvt_x<<<4096, 256, 0, stream>>>(x, xb);
  dim3 tb(32, 8);
  k_twb<<<dim3(32, 32), tb, 0, stream>>>(Wq, wtq);
  k_twb<<<dim3(32, 32), tb, 0, stream>>>(Wk, wtk);
  k_twb<<<dim3(32, 32), tb, 0, stream>>>(Wv, wtv);
  k_qkv<<<dim3(8, 32, 3), 256, 0, stream>>>(xb, wtq, wtk, wtv, qb, kb, vtb);
  k_cstat<<<dim3(32, 16), 256, 0, stream>>>(qb, kb, vtb);
  k_ctx<<<dim3(32, 8), 512, 0, stream>>>(qb, kb, vtb, out);
}